// Round 15
// baseline (43.113 us; speedup 1.0000x reference)
//
#include <hip/hip_runtime.h>
#include <math.h>

// Problem: B=64, T=512, D=1024.
//   v[b,d]     = sum_e W[d,e] * x[b,T-1,e]
//   scores[b,t]= sum_d x[b,t,d] * v[b,d]          (t in 0..510)
//   alpha      = softmax_t(scores)
//   c[b,d]     = sum_t alpha[b,t] * x[b,t,d]
//   out[b]     = concat(c[b,:], x[b,T-1,:])       (64 x 2048 fp32)
//
// HISTORY:
//  R4  flash G16 prefetch, paired rows           49.3 us
//  R5-R9 fused finalize w/ __threadfence         ~200 us (L2 wb/inv -> dead end)
//  R10 flash G32 lb(256,4)                       52.0 us
//  R11 two-pass (x read twice)                   68.1 us (+16us = 2nd pass BW)
//  R12 k_v 4x parallel + k_chunk lb(256,6) TLP   41.3 us
//  R13 acc in LDS, 8 waves/SIMD                  44.8 us (DS RMW in dep path)
//  R14 paired rows, one rescale per pair         42.7 us (neutral: chain not binding?)
//  R15: QUAD-shot — all 4 wave rows loaded at once (16KB loads in flight),
//       4 independent dot+butterfly chains, ONE softmax step, NO online
//       rescale at all. ~90 VGPR -> lb(256,5). If still ~41us: k_chunk inner
//       loop exonerated -> instrument next (k_chunk x3) to find fixed cost.

#define BB 64
#define TT 512
#define DD 1024
#define TH 511           // valid history rows: 0..510
#define GROUPS 32        // blocks per batch
#define RPW 4            // rows per wave (4 waves * 4 = 16 rows per block)

// workspace (floats):
//   v      : [BB][DD]          off 0            (65536)
//   partC  : [BB][GROUPS][DD]  off 65536        (2097152, 8 MB)
//   partML : [BB][GROUPS][2]   off 2162688      (4096)

// ---------------- kernel 1: v = x_last @ W^T -------------------------------
// 1024 blocks x 4 waves; wave = 4 d-rows (W stationary) x 4 batches.
// x_last (256KB) stays L2-hot across the 32 blocks/XCD that re-read it.
__global__ __launch_bounds__(256, 4) void k_v(const float* __restrict__ x,
                                              const float* __restrict__ W,
                                              float* __restrict__ v) {
    const int wave = threadIdx.x >> 6;
    const int lane = threadIdx.x & 63;
    const int wg   = blockIdx.x * 4 + wave;   // 0..4095
    const int d0   = (wg >> 4) * 4;           // 256 d-quads
    const int bg   = wg & 15;                 // 16 batch-groups of 4

    float4 w4[4][4];
#pragma unroll
    for (int k = 0; k < 4; ++k)
#pragma unroll
        for (int j = 0; j < 4; ++j)
            w4[k][j] = *(const float4*)(W + (size_t)(d0 + k) * DD + j * 256 + lane * 4);

    float res = 0.f;                          // lanes 0..15: (b=bg*4+(l>>2), d=d0+(l&3))
#pragma unroll
    for (int i = 0; i < 4; ++i) {
        const int b = bg * 4 + i;
        const float* xl = x + ((size_t)b * TT + (TT - 1)) * DD;
        float4 x4[4];
#pragma unroll
        for (int j = 0; j < 4; ++j)
            x4[j] = *(const float4*)(xl + j * 256 + lane * 4);
        float p[4];
#pragma unroll
        for (int k = 0; k < 4; ++k)
            p[k] = w4[k][0].x * x4[0].x + w4[k][0].y * x4[0].y + w4[k][0].z * x4[0].z + w4[k][0].w * x4[0].w
                 + w4[k][1].x * x4[1].x + w4[k][1].y * x4[1].y + w4[k][1].z * x4[1].z + w4[k][1].w * x4[1].w
                 + w4[k][2].x * x4[2].x + w4[k][2].y * x4[2].y + w4[k][2].z * x4[2].z + w4[k][2].w * x4[2].w
                 + w4[k][3].x * x4[3].x + w4[k][3].y * x4[3].y + w4[k][3].z * x4[3].z + w4[k][3].w * x4[3].w;
#pragma unroll
        for (int mm = 1; mm < 64; mm <<= 1) {
#pragma unroll
            for (int k = 0; k < 4; ++k) p[k] += __shfl_xor(p[k], mm, 64);
        }
#pragma unroll
        for (int k = 0; k < 4; ++k)
            if (lane == i * 4 + k) res = p[k];
    }
    if (lane < 16)
        v[(size_t)(bg * 4 + (lane >> 2)) * DD + d0 + (lane & 3)] = res;
}

// ---------------- kernel 2: quad-shot chunk (no online softmax) ------------
// 2048 blocks (64 b x 32 groups), 256 thr, lb(256,5) (~90 VGPR, cap 102).
// Wave: 4 rows loaded AT ONCE, 4 independent dot+butterfly chains, ONE
// softmax step (max/exp/accumulate), no rescale. Named scalars throughout.
__global__ __launch_bounds__(256, 5) void k_chunk(const float* __restrict__ x,
                                                  const float* __restrict__ v,
                                                  float* __restrict__ partC,
                                                  float* __restrict__ partML) {
    __shared__ float cw[4][DD];               // 16 KB combine buffer
    __shared__ float cml[4][2];

    const int b    = blockIdx.x >> 5;         // / GROUPS
    const int g    = blockIdx.x & (GROUPS - 1);
    const int wave = threadIdx.x >> 6;
    const int lane = threadIdx.x & 63;
    const int r0   = g * 16 + wave * RPW;     // <= 508
    const int col  = lane * 4;

    const float* xbase = x + (size_t)b * TT * DD;
    const float* vb = v + (size_t)b * DD + col;
    const float4 vv0 = *(const float4*)(vb);
    const float4 vv1 = *(const float4*)(vb + 256);
    const float4 vv2 = *(const float4*)(vb + 512);
    const float4 vv3 = *(const float4*)(vb + 768);

    // rows r0..r0+2 always valid (r0 <= 508); only r0+3 can be 511 -> clamp+mask
    const float* pa = xbase + (size_t)r0 * DD + col;
    const float* pb = xbase + (size_t)(r0 + 1) * DD + col;
    const float* pc = xbase + (size_t)(r0 + 2) * DD + col;
    const float* pd = xbase + (size_t)min(r0 + 3, TH - 1) * DD + col;

    const float4 xa0 = *(const float4*)(pa);
    const float4 xa1 = *(const float4*)(pa + 256);
    const float4 xa2 = *(const float4*)(pa + 512);
    const float4 xa3 = *(const float4*)(pa + 768);
    const float4 xb0 = *(const float4*)(pb);
    const float4 xb1 = *(const float4*)(pb + 256);
    const float4 xb2 = *(const float4*)(pb + 512);
    const float4 xb3 = *(const float4*)(pb + 768);
    const float4 xc0 = *(const float4*)(pc);
    const float4 xc1 = *(const float4*)(pc + 256);
    const float4 xc2 = *(const float4*)(pc + 512);
    const float4 xc3 = *(const float4*)(pc + 768);
    const float4 xd0 = *(const float4*)(pd);
    const float4 xd1 = *(const float4*)(pd + 256);
    const float4 xd2 = *(const float4*)(pd + 512);
    const float4 xd3 = *(const float4*)(pd + 768);

    float s0 = vv0.x*xa0.x + vv0.y*xa0.y + vv0.z*xa0.z + vv0.w*xa0.w
             + vv1.x*xa1.x + vv1.y*xa1.y + vv1.z*xa1.z + vv1.w*xa1.w
             + vv2.x*xa2.x + vv2.y*xa2.y + vv2.z*xa2.z + vv2.w*xa2.w
             + vv3.x*xa3.x + vv3.y*xa3.y + vv3.z*xa3.z + vv3.w*xa3.w;
    float s1 = vv0.x*xb0.x + vv0.y*xb0.y + vv0.z*xb0.z + vv0.w*xb0.w
             + vv1.x*xb1.x + vv1.y*xb1.y + vv1.z*xb1.z + vv1.w*xb1.w
             + vv2.x*xb2.x + vv2.y*xb2.y + vv2.z*xb2.z + vv2.w*xb2.w
             + vv3.x*xb3.x + vv3.y*xb3.y + vv3.z*xb3.z + vv3.w*xb3.w;
    float s2 = vv0.x*xc0.x + vv0.y*xc0.y + vv0.z*xc0.z + vv0.w*xc0.w
             + vv1.x*xc1.x + vv1.y*xc1.y + vv1.z*xc1.z + vv1.w*xc1.w
             + vv2.x*xc2.x + vv2.y*xc2.y + vv2.z*xc2.z + vv2.w*xc2.w
             + vv3.x*xc3.x + vv3.y*xc3.y + vv3.z*xc3.z + vv3.w*xc3.w;
    float s3 = vv0.x*xd0.x + vv0.y*xd0.y + vv0.z*xd0.z + vv0.w*xd0.w
             + vv1.x*xd1.x + vv1.y*xd1.y + vv1.z*xd1.z + vv1.w*xd1.w
             + vv2.x*xd2.x + vv2.y*xd2.y + vv2.z*xd2.z + vv2.w*xd2.w
             + vv3.x*xd3.x + vv3.y*xd3.y + vv3.z*xd3.z + vv3.w*xd3.w;

#pragma unroll
    for (int mm = 1; mm < 64; mm <<= 1) {      // 4 independent butterflies
        s0 += __shfl_xor(s0, mm, 64);
        s1 += __shfl_xor(s1, mm, 64);
        s2 += __shfl_xor(s2, mm, 64);
        s3 += __shfl_xor(s3, mm, 64);
    }
    if (r0 + 3 >= TH) s3 = -INFINITY;          // only row that can be invalid

    // single softmax step (all values wave-uniform)
    const float mw = fmaxf(fmaxf(s0, s1), fmaxf(s2, s3));
    const float e0 = __expf(s0 - mw);
    const float e1 = __expf(s1 - mw);
    const float e2 = __expf(s2 - mw);
    const float e3 = __expf(s3 - mw);
    const float lw = e0 + e1 + e2 + e3;

    float4 a0, a1, a2, a3;
    a0.x = e0*xa0.x + e1*xb0.x + e2*xc0.x + e3*xd0.x;
    a0.y = e0*xa0.y + e1*xb0.y + e2*xc0.y + e3*xd0.y;
    a0.z = e0*xa0.z + e1*xb0.z + e2*xc0.z + e3*xd0.z;
    a0.w = e0*xa0.w + e1*xb0.w + e2*xc0.w + e3*xd0.w;
    a1.x = e0*xa1.x + e1*xb1.x + e2*xc1.x + e3*xd1.x;
    a1.y = e0*xa1.y + e1*xb1.y + e2*xc1.y + e3*xd1.y;
    a1.z = e0*xa1.z + e1*xb1.z + e2*xc1.z + e3*xd1.z;
    a1.w = e0*xa1.w + e1*xb1.w + e2*xc1.w + e3*xd1.w;
    a2.x = e0*xa2.x + e1*xb2.x + e2*xc2.x + e3*xd2.x;
    a2.y = e0*xa2.y + e1*xb2.y + e2*xc2.y + e3*xd2.y;
    a2.z = e0*xa2.z + e1*xb2.z + e2*xc2.z + e3*xd2.z;
    a2.w = e0*xa2.w + e1*xb2.w + e2*xc2.w + e3*xd2.w;
    a3.x = e0*xa3.x + e1*xb3.x + e2*xc3.x + e3*xd3.x;
    a3.y = e0*xa3.y + e1*xb3.y + e2*xc3.y + e3*xd3.y;
    a3.z = e0*xa3.z + e1*xb3.z + e2*xc3.z + e3*xd3.z;
    a3.w = e0*xa3.w + e1*xb3.w + e2*xc3.w + e3*xd3.w;

    *(float4*)(&cw[wave][0 * 256 + col]) = a0;
    *(float4*)(&cw[wave][1 * 256 + col]) = a1;
    *(float4*)(&cw[wave][2 * 256 + col]) = a2;
    *(float4*)(&cw[wave][3 * 256 + col]) = a3;
    if (lane == 0) { cml[wave][0] = mw; cml[wave][1] = lw; }
    __syncthreads();

    const float M = fmaxf(fmaxf(cml[0][0], cml[1][0]), fmaxf(cml[2][0], cml[3][0]));
    const float w0 = __expf(cml[0][0] - M), w1 = __expf(cml[1][0] - M);
    const float w2 = __expf(cml[2][0] - M), w3 = __expf(cml[3][0] - M);
    const float L = w0 * cml[0][1] + w1 * cml[1][1] + w2 * cml[2][1] + w3 * cml[3][1];

    const int d0 = threadIdx.x * 4;
    const float4 t0 = *(const float4*)(&cw[0][d0]);
    const float4 t1 = *(const float4*)(&cw[1][d0]);
    const float4 t2 = *(const float4*)(&cw[2][d0]);
    const float4 t3 = *(const float4*)(&cw[3][d0]);
    float4 o;
    o.x = w0 * t0.x + w1 * t1.x + w2 * t2.x + w3 * t3.x;
    o.y = w0 * t0.y + w1 * t1.y + w2 * t2.y + w3 * t3.y;
    o.z = w0 * t0.z + w1 * t1.z + w2 * t2.z + w3 * t3.z;
    o.w = w0 * t0.w + w1 * t1.w + w2 * t2.w + w3 * t3.w;
    *(float4*)(partC + ((size_t)b * GROUPS + g) * DD + d0) = o;
    if (threadIdx.x == 0) {
        partML[((size_t)b * GROUPS + g) * 2 + 0] = M;
        partML[((size_t)b * GROUPS + g) * 2 + 1] = L;
    }
}

// ---------------- kernel 3: combine partials, divide, append x_last --------
__global__ __launch_bounds__(256) void k_final(const float* __restrict__ x,
                                               const float* __restrict__ partC,
                                               const float* __restrict__ partML,
                                               float* __restrict__ out) {
    const int b = blockIdx.x >> 2;
    const int q = blockIdx.x & 3;
    __shared__ float wgt[GROUPS];
    __shared__ float lsh;

    if (threadIdx.x < GROUPS) {
        float M = -INFINITY;
        for (int cc = 0; cc < GROUPS; ++cc)
            M = fmaxf(M, partML[((size_t)b * GROUPS + cc) * 2]);
        wgt[threadIdx.x] = __expf(partML[((size_t)b * GROUPS + threadIdx.x) * 2] - M);
    }
    __syncthreads();
    if (threadIdx.x == 0) {
        float L = 0.f;
        for (int cc = 0; cc < GROUPS; ++cc)
            L += partML[((size_t)b * GROUPS + cc) * 2 + 1] * wgt[cc];
        lsh = 1.f / L;
    }
    __syncthreads();
    const float invL = lsh;

    const int d = q * 256 + threadIdx.x;
    float acc = 0.f;
#pragma unroll 8
    for (int cc = 0; cc < GROUPS; ++cc)
        acc += wgt[cc] * partC[((size_t)b * GROUPS + cc) * DD + d];
    out[(size_t)b * 2048 + d] = acc * invL;
    out[(size_t)b * 2048 + 1024 + d] = x[((size_t)b * TT + (TT - 1)) * DD + d];
}

extern "C" void kernel_launch(void* const* d_in, const int* in_sizes, int n_in,
                              void* d_out, int out_size, void* d_ws, size_t ws_size,
                              hipStream_t stream) {
    const float* x = (const float*)d_in[0];   // (64,512,1024) fp32
    const float* W = (const float*)d_in[1];   // (1024,1024) fp32
    float* out = (float*)d_out;               // (64,2048) fp32

    float* ws     = (float*)d_ws;             // ~8.5 MB
    float* v      = ws;                                           // 65536
    float* partC  = ws + 65536;                                   // 2097152
    float* partML = ws + 65536 + (size_t)BB * GROUPS * DD;        // 4096

    k_v<<<1024, 256, 0, stream>>>(x, W, v);
    k_chunk<<<BB * GROUPS, 256, 0, stream>>>(x, v, partC, partML);
    k_final<<<BB * 4, 256, 0, stream>>>(x, partC, partML, out);
}